// Round 6
// baseline (436.027 us; speedup 1.0000x reference)
//
#include <hip/hip_runtime.h>
#include <math.h>

#define MIN_NORM 1e-15f
#define BALL_EPS 0.004f

constexpr int D  = 256;
constexpr int NQ = 200000;
constexpr float SCALE = 0.0625f;   // 1/sqrt(256)

typedef float f32x4 __attribute__((ext_vector_type(4)));

__device__ __forceinline__ void nt_store4(float* p, f32x4 v) {
    __builtin_nontemporal_store(v, (f32x4*)p);      // single dwordx4 nt store
}

__device__ __forceinline__ f32x4 nt_load4(const float* p) {
    return __builtin_nontemporal_load((const f32x4*)p);  // dwordx4 nt load (no L2 alloc)
}

__device__ __forceinline__ f32x4 ld4(const float* p) {
    return *(const f32x4*)p;
}

// 4 batched reductions over each 32-lane half (xor offsets < 32 keep halves independent)
__device__ __forceinline__ void half_sum4(float& a, float& b, float& c, float& d) {
    #pragma unroll
    for (int off = 16; off > 0; off >>= 1) {
        a += __shfl_xor(a, off, 64);
        b += __shfl_xor(b, off, 64);
        c += __shfl_xor(c, off, 64);
        d += __shfl_xor(d, off, 64);
    }
}

__device__ __forceinline__ void unpack8(f32x4 a, f32x4 b, float* d) {
    d[0] = a.x; d[1] = a.y; d[2] = a.z; d[3] = a.w;
    d[4] = b.x; d[5] = b.y; d[6] = b.z; d[7] = b.w;
}

__device__ __forceinline__ float tanh_pos(float x) {   // x >= 0
    const float e = __expf(-2.0f * x);
    return (1.0f - e) / (1.0f + e);
}

__global__ __launch_bounds__(256) void atth_kernel(
    const int*   __restrict__ queries,
    const float* __restrict__ entity_emb,
    const float* __restrict__ rel_emb,
    const float* __restrict__ bias_head,
    const float* __restrict__ bias_tail,
    const float* __restrict__ c_arr,
    const float* __restrict__ att_rel_emb,
    const float* __restrict__ context_emb,
    float*       __restrict__ out)
{
    const int lane = threadIdx.x & 63;
    const int hl   = lane & 31;                       // lane within 32-half
    const int qid  = blockIdx.x * 8 + (threadIdx.x >> 5);
    if (qid >= NQ) return;

    const int h = queries[qid * 3 + 0];
    const int r = queries[qid * 3 + 1];
    const int t = queries[qid * 3 + 2];

    // c_q = softplus(c[r])   (stable form)
    const float craw   = c_arr[r];
    const float cq     = fmaxf(craw, 0.0f) + log1pf(__expf(-fabsf(craw)));
    const float sqrt_c = sqrtf(cq);

    const int e8 = hl * 8;

    const float* eh = entity_emb  + (size_t)h * D     + e8;
    const float* et = entity_emb  + (size_t)t * D     + e8;
    const float* rr = rel_emb     + (size_t)r * 2 * D + e8;
    const float* am = att_rel_emb + (size_t)r * 2 * D + e8;
    const float* cb = context_emb + (size_t)r * D     + e8;

    // entity gathers: non-temporal (don't pollute L2 -> relation tables stay resident)
    const f32x4 h0 = nt_load4(eh);     const f32x4 h1 = nt_load4(eh + 4);
    const f32x4 t0 = nt_load4(et);     const f32x4 t1 = nt_load4(et + 4);
    // relation-indexed tables: normal cached loads (hot ~5 MB working set)
    const f32x4 r0 = ld4(rr);     const f32x4 r1 = ld4(rr + 4);
    const f32x4 r2 = ld4(rr + D); const f32x4 r3 = ld4(rr + D + 4);
    const f32x4 m0 = ld4(am);     const f32x4 m1 = ld4(am + 4);
    const f32x4 f0 = ld4(am + D); const f32x4 f1 = ld4(am + D + 4);
    const f32x4 ct0 = ld4(cb);    const f32x4 ct1 = ld4(cb + 4);

    // --- streaming copies to output, issued early so they overlap compute ---
    float* out_pred = out;
    float* out_head = out + (size_t)NQ;
    float* out_rel  = out + (size_t)NQ + (size_t)NQ * D;
    float* out_tail = out + (size_t)NQ + (size_t)NQ * D + (size_t)NQ * 2 * D;

    nt_store4(out_head + (size_t)qid * D         + e8,     h0);
    nt_store4(out_head + (size_t)qid * D         + e8 + 4, h1);
    nt_store4(out_rel  + (size_t)qid * 2 * D     + e8,     r0);
    nt_store4(out_rel  + (size_t)qid * 2 * D     + e8 + 4, r1);
    nt_store4(out_rel  + (size_t)qid * 2 * D + D + e8,     r2);
    nt_store4(out_rel  + (size_t)qid * 2 * D + D + e8 + 4, r3);
    nt_store4(out_tail + (size_t)qid * D         + e8,     t0);
    nt_store4(out_tail + (size_t)qid * D         + e8 + 4, t1);

    float hd[8], tl[8], rl[8], rm[8], fm[8], cx[8];
    unpack8(h0, h1, hd);
    unpack8(t0, t1, tl);
    unpack8(r0, r1, rl);
    unpack8(m0, m1, rm);
    unpack8(f0, f1, fm);
    unpack8(ct0, ct1, cx);

    // Givens rotation + reflection on 4 local pairs (rsqrt instead of div+sqrt)
    float rq[8], fq[8];
    #pragma unroll
    for (int p = 0; p < 4; ++p) {
        const int i0 = 2 * p, i1 = 2 * p + 1;
        float s   = rm[i0] * rm[i0] + rm[i1] * rm[i1];
        float inv = rsqrtf(fmaxf(s, 1e-30f));          // == 1/max(sqrt(s),1e-15)
        const float g0 = rm[i0] * inv, g1 = rm[i1] * inv;
        rq[i0] = g0 * hd[i0] - g1 * hd[i1];
        rq[i1] = g0 * hd[i1] + g1 * hd[i0];
        s   = fm[i0] * fm[i0] + fm[i1] * fm[i1];
        inv = rsqrtf(fmaxf(s, 1e-30f));
        const float e0 = fm[i0] * inv, e1 = fm[i1] * inv;
        fq[i0] = e0 * hd[i0] + e1 * hd[i1];
        fq[i1] = e1 * hd[i0] - e0 * hd[i1];
    }

    // ---- reduction stage 1: sref, srot, ||rl||^2, ||tail||^2 ----
    float sref = 0.0f, srot = 0.0f, url2 = 0.0f, sv = 0.0f;
    #pragma unroll
    for (int j = 0; j < 8; ++j) {
        sref += cx[j] * fq[j];
        srot += cx[j] * rq[j];
        url2 += rl[j] * rl[j];
        sv   += tl[j] * tl[j];
    }
    half_sum4(sref, srot, url2, sv);
    sref *= SCALE; srot *= SCALE;

    // softmax over the 2 candidates
    const float mx   = fmaxf(sref, srot);
    const float eref = __expf(sref - mx), erot = __expf(srot - mx);
    const float inv_se = 1.0f / (eref + erot);
    const float wref = eref * inv_se, wrot = erot * inv_se;

    float att[8];
    #pragma unroll
    for (int j = 0; j < 8; ++j) att[j] = wref * fq[j] + wrot * rq[j];

    // ---- reduction stage 2: ||att||^2, att.rl, att.tail, rl.tail ----
    float u2 = 0.0f, adr = 0.0f, atl = 0.0f, rtl = 0.0f;
    #pragma unroll
    for (int j = 0; j < 8; ++j) {
        u2  += att[j] * att[j];
        adr += att[j] * rl[j];
        atl += att[j] * tl[j];
        rtl += rl[j]  * tl[j];
    }
    half_sum4(u2, adr, atl, rtl);

    // ---- all remaining math is scalar (uniform within the half-wave) ----
    const float maxnorm = (1.0f - BALL_EPS) / sqrt_c;

    // lhs = project(expmap0(att, c)): lhs = sA * att
    const float u    = fmaxf(sqrtf(u2), MIN_NORM);
    const float facA = tanh_pos(sqrt_c * u) / (sqrt_c * u);
    const float nA   = facA * u;                          // ||expmap0(att)||
    const float sA   = facA * ((nA > maxnorm) ? maxnorm / nA : 1.0f);
    const float x2   = sA * sA * u2;

    // rh = project(expmap0(rl, c)): rh = sB * rl
    const float url  = fmaxf(sqrtf(url2), MIN_NORM);
    const float facB = tanh_pos(sqrt_c * url) / (sqrt_c * url);
    const float nB   = facB * url;
    const float sB   = facB * ((nB > maxnorm) ? maxnorm / nB : 1.0f);
    const float y2   = sB * sB * url2;

    const float xy = sA * sB * adr;

    // mobius_add(lhs, rh, c): res = pA*att + pB*rl
    const float ka  = 1.0f + 2.0f * cq * xy + cq * y2;
    const float kb  = 1.0f - cq * x2;
    const float den = fmaxf(1.0f + 2.0f * cq * xy + cq * cq * x2 * y2, MIN_NORM);
    const float pA  = ka * sA / den;
    const float pB  = kb * sB / den;

    // project(res, c) analytically
    const float rn2 = pA * pA * u2 + 2.0f * pA * pB * adr + pB * pB * url2;
    const float nrm = fmaxf(sqrtf(rn2), MIN_NORM);
    const float pr  = (nrm > maxnorm) ? maxnorm / nrm : 1.0f;
    const float rx2 = rn2 * pr * pr;

    // hyp_distance(res, tail, c)^2
    const float vnorm = fmaxf(sqrtf(sv), MIN_NORM);
    const float sxv   = (pA * atl + pB * rtl) * pr;       // res . tail
    const float xv    = sxv / vnorm;
    const float gamma = tanh_pos(sqrt_c * vnorm) / vnorm;
    const float k1 = 1.0f - 2.0f * cq * gamma * xv + cq * gamma * gamma;
    const float k2 = 1.0f - cq * rx2;
    const float num = sqrtf(fmaxf(k1 * k1 * rx2 + k2 * k2 * gamma * gamma
                                  - 2.0f * k1 * k2 * gamma * xv, 0.0f));
    const float dden = fmaxf(1.0f - 2.0f * cq * gamma * xv
                             + cq * cq * gamma * gamma * rx2, MIN_NORM);
    float arg = sqrt_c * num / dden;
    arg = fminf(fmaxf(arg, -1.0f + 1e-5f), 1.0f - 1e-5f);
    const float ath  = 0.5f * __logf((1.0f + arg) / (1.0f - arg));
    const float dist = 2.0f * ath / sqrt_c;
    const float dist2 = dist * dist;

    if (hl == 0) {
        __builtin_nontemporal_store(bias_head[h] + bias_tail[t] + dist2, out_pred + qid);
    }
}

extern "C" void kernel_launch(void* const* d_in, const int* in_sizes, int n_in,
                              void* d_out, int out_size, void* d_ws, size_t ws_size,
                              hipStream_t stream) {
    const int*   queries     = (const int*)  d_in[0];
    const float* entity_emb  = (const float*)d_in[1];
    const float* rel_emb     = (const float*)d_in[2];
    const float* bias_head   = (const float*)d_in[3];
    const float* bias_tail   = (const float*)d_in[4];
    const float* c_arr       = (const float*)d_in[5];
    const float* att_rel_emb = (const float*)d_in[6];
    const float* context_emb = (const float*)d_in[7];
    float* out = (float*)d_out;

    const int queries_per_block = 8;                 // 8 half-waves of 32
    const int grid = (NQ + queries_per_block - 1) / queries_per_block;
    atth_kernel<<<grid, 256, 0, stream>>>(queries, entity_emb, rel_emb,
                                          bias_head, bias_tail, c_arr,
                                          att_rel_emb, context_emb, out);
}

// Round 7
// 304.812 us; speedup vs baseline: 1.4305x; 1.4305x over previous
//
#include <hip/hip_runtime.h>
#include <math.h>

#define MIN_NORM 1e-15f
#define BALL_EPS 0.004f

constexpr int D  = 256;
constexpr int R  = 1000;
constexpr int NQ = 200000;
constexpr float SCALE = 0.0625f;   // 1/sqrt(256)

typedef float  f32x4  __attribute__((ext_vector_type(4)));
typedef unsigned short u16x8 __attribute__((ext_vector_type(8)));

__device__ __forceinline__ void nt_store4(float* p, f32x4 v) {
    __builtin_nontemporal_store(v, (f32x4*)p);
}
__device__ __forceinline__ f32x4 ld4(const float* p) { return *(const f32x4*)p; }

__device__ __forceinline__ unsigned short f2bf(float x) {   // round-to-nearest-even
    unsigned int u = __float_as_uint(x);
    u += 0x7fffu + ((u >> 16) & 1u);
    return (unsigned short)(u >> 16);
}
__device__ __forceinline__ float bf2f(unsigned short u) {
    return __uint_as_float(((unsigned int)u) << 16);
}

__device__ __forceinline__ void half_sum4(float& a, float& b, float& c, float& d) {
    #pragma unroll
    for (int off = 16; off > 0; off >>= 1) {
        a += __shfl_xor(a, off, 64);
        b += __shfl_xor(b, off, 64);
        c += __shfl_xor(c, off, 64);
        d += __shfl_xor(d, off, 64);
    }
}
__device__ __forceinline__ void half_sum3(float& a, float& b, float& c) {
    #pragma unroll
    for (int off = 16; off > 0; off >>= 1) {
        a += __shfl_xor(a, off, 64);
        b += __shfl_xor(b, off, 64);
        c += __shfl_xor(c, off, 64);
    }
}

__device__ __forceinline__ void unpack8(f32x4 a, f32x4 b, float* d) {
    d[0] = a.x; d[1] = a.y; d[2] = a.z; d[3] = a.w;
    d[4] = b.x; d[5] = b.y; d[6] = b.z; d[7] = b.w;
}

__device__ __forceinline__ float tanh_pos(float x) {   // x >= 0
    const float e = __expf(-2.0f * x);
    return (1.0f - e) / (1.0f + e);
}

// ---------------- per-relation precompute (1000 waves) ----------------
// ws layout: scal f32[R*8] | rot u16[R*256] | ref u16[R*256] | ctx u16[R*256]
__global__ __launch_bounds__(64) void prep_kernel(
    const float* __restrict__ rel_emb,
    const float* __restrict__ c_arr,
    const float* __restrict__ att_rel_emb,
    const float* __restrict__ context_emb,
    float* __restrict__ ws_scal,
    unsigned short* __restrict__ ws_rot,
    unsigned short* __restrict__ ws_ref,
    unsigned short* __restrict__ ws_ctx)
{
    const int r    = blockIdx.x;
    const int lane = threadIdx.x;        // 64 lanes, 4 elems each

    const float craw   = c_arr[r];
    const float cq     = fmaxf(craw, 0.0f) + log1pf(__expf(-fabsf(craw)));
    const float sqrt_c = sqrtf(cq);
    const float maxnorm = (1.0f - BALL_EPS) / sqrt_c;

    const float* am = att_rel_emb + (size_t)r * 2 * D + lane * 4;
    const float* cb = context_emb + (size_t)r * D     + lane * 4;
    const float* rr = rel_emb     + (size_t)r * 2 * D + lane * 4;

    float rotn[4], refn[4];
    #pragma unroll
    for (int p = 0; p < 2; ++p) {
        const float a0 = am[2*p], a1 = am[2*p+1];
        float inv = rsqrtf(fmaxf(a0*a0 + a1*a1, 1e-30f));
        rotn[2*p] = a0*inv; rotn[2*p+1] = a1*inv;
        const float b0 = am[D + 2*p], b1 = am[D + 2*p+1];
        inv = rsqrtf(fmaxf(b0*b0 + b1*b1, 1e-30f));
        refn[2*p] = b0*inv; refn[2*p+1] = b1*inv;
    }

    float url2 = 0.0f;
    float ctxs[4];
    #pragma unroll
    for (int j = 0; j < 4; ++j) {
        ctxs[j] = cb[j] * SCALE;
        const float v = rr[j];
        url2 += v * v;
    }
    #pragma unroll
    for (int off = 32; off > 0; off >>= 1) url2 += __shfl_xor(url2, off, 64);

    const float url  = fmaxf(sqrtf(url2), MIN_NORM);
    const float facB = tanh_pos(sqrt_c * url) / (sqrt_c * url);
    const float nB   = facB * url;
    const float sB   = facB * ((nB > maxnorm) ? maxnorm / nB : 1.0f);
    const float y2   = sB * sB * url2;

    #pragma unroll
    for (int j = 0; j < 4; ++j) {
        ws_rot[(size_t)r * D + lane*4 + j] = f2bf(rotn[j]);
        ws_ref[(size_t)r * D + lane*4 + j] = f2bf(refn[j]);
        ws_ctx[(size_t)r * D + lane*4 + j] = f2bf(ctxs[j]);
    }
    if (lane == 0) {
        float* s = ws_scal + (size_t)r * 8;
        s[0] = cq; s[1] = sqrt_c; s[2] = maxnorm; s[3] = sB; s[4] = y2;
    }
}

// ---------------- main kernel ----------------
__global__ __launch_bounds__(256) void atth_kernel(
    const int*   __restrict__ queries,
    const float* __restrict__ entity_emb,
    const float* __restrict__ rel_emb,
    const float* __restrict__ bias_head,
    const float* __restrict__ bias_tail,
    const float* __restrict__ ws_scal,
    const unsigned short* __restrict__ ws_rot,
    const unsigned short* __restrict__ ws_ref,
    const unsigned short* __restrict__ ws_ctx,
    float*       __restrict__ out)
{
    const int lane = threadIdx.x & 63;
    const int hl   = lane & 31;
    const int qid  = blockIdx.x * 8 + (threadIdx.x >> 5);
    if (qid >= NQ) return;

    const int h = queries[qid * 3 + 0];
    const int r = queries[qid * 3 + 1];
    const int t = queries[qid * 3 + 2];

    const float* sc = ws_scal + (size_t)r * 8;
    const float cq = sc[0], sqrt_c = sc[1], maxnorm = sc[2], sB = sc[3], y2 = sc[4];

    const int e8 = hl * 8;

    const float* eh = entity_emb + (size_t)h * D     + e8;
    const float* et = entity_emb + (size_t)t * D     + e8;
    const float* rr = rel_emb    + (size_t)r * 2 * D + e8;

    // entity + rel reads: cached (L2/L3 reuse matters — R6 proved it)
    const f32x4 h0 = ld4(eh);     const f32x4 h1 = ld4(eh + 4);
    const f32x4 t0 = ld4(et);     const f32x4 t1 = ld4(et + 4);
    const f32x4 r0 = ld4(rr);     const f32x4 r1 = ld4(rr + 4);
    const f32x4 r2 = ld4(rr + D); const f32x4 r3 = ld4(rr + D + 4);
    const u16x8 rotv = *(const u16x8*)(ws_rot + (size_t)r * D + e8);
    const u16x8 refv = *(const u16x8*)(ws_ref + (size_t)r * D + e8);
    const u16x8 ctxv = *(const u16x8*)(ws_ctx + (size_t)r * D + e8);

    // streaming output copies (non-temporal)
    float* out_pred = out;
    float* out_head = out + (size_t)NQ;
    float* out_rel  = out + (size_t)NQ + (size_t)NQ * D;
    float* out_tail = out + (size_t)NQ + (size_t)NQ * D + (size_t)NQ * 2 * D;

    nt_store4(out_head + (size_t)qid * D         + e8,     h0);
    nt_store4(out_head + (size_t)qid * D         + e8 + 4, h1);
    nt_store4(out_rel  + (size_t)qid * 2 * D     + e8,     r0);
    nt_store4(out_rel  + (size_t)qid * 2 * D     + e8 + 4, r1);
    nt_store4(out_rel  + (size_t)qid * 2 * D + D + e8,     r2);
    nt_store4(out_rel  + (size_t)qid * 2 * D + D + e8 + 4, r3);
    nt_store4(out_tail + (size_t)qid * D         + e8,     t0);
    nt_store4(out_tail + (size_t)qid * D         + e8 + 4, t1);

    float hd[8], tl[8], rl[8];
    unpack8(h0, h1, hd);
    unpack8(t0, t1, tl);
    unpack8(r0, r1, rl);

    // Givens with pre-normalized bf16 coefficients
    float rq[8], fq[8];
    #pragma unroll
    for (int p = 0; p < 4; ++p) {
        const int i0 = 2*p, i1 = 2*p + 1;
        const float g0 = bf2f(rotv[i0]), g1 = bf2f(rotv[i1]);
        rq[i0] = g0 * hd[i0] - g1 * hd[i1];
        rq[i1] = g0 * hd[i1] + g1 * hd[i0];
        const float e0 = bf2f(refv[i0]), e1 = bf2f(refv[i1]);
        fq[i0] = e0 * hd[i0] + e1 * hd[i1];
        fq[i1] = e1 * hd[i0] - e0 * hd[i1];
    }

    // stage 1: sref, srot, ||tail||^2, rl.tail
    float sref = 0.0f, srot = 0.0f, sv = 0.0f, rtl = 0.0f;
    #pragma unroll
    for (int j = 0; j < 8; ++j) {
        const float cxj = bf2f(ctxv[j]);          // already * SCALE
        sref += cxj * fq[j];
        srot += cxj * rq[j];
        sv   += tl[j] * tl[j];
        rtl  += rl[j] * tl[j];
    }
    half_sum4(sref, srot, sv, rtl);

    const float mx   = fmaxf(sref, srot);
    const float eref = __expf(sref - mx), erot = __expf(srot - mx);
    const float inv_se = 1.0f / (eref + erot);
    const float wref = eref * inv_se, wrot = erot * inv_se;

    float att[8];
    #pragma unroll
    for (int j = 0; j < 8; ++j) att[j] = wref * fq[j] + wrot * rq[j];

    // stage 2: ||att||^2, att.rl, att.tail
    float u2 = 0.0f, adr = 0.0f, atl = 0.0f;
    #pragma unroll
    for (int j = 0; j < 8; ++j) {
        u2  += att[j] * att[j];
        adr += att[j] * rl[j];
        atl += att[j] * tl[j];
    }
    half_sum3(u2, adr, atl);

    // scalar epilogue (uniform per half-wave)
    const float u    = fmaxf(sqrtf(u2), MIN_NORM);
    const float facA = tanh_pos(sqrt_c * u) / (sqrt_c * u);
    const float nA   = facA * u;
    const float sA   = facA * ((nA > maxnorm) ? maxnorm / nA : 1.0f);
    const float x2   = sA * sA * u2;

    const float xy = sA * sB * adr;          // lhs . rh

    const float ka  = 1.0f + 2.0f * cq * xy + cq * y2;
    const float kb  = 1.0f - cq * x2;
    const float den = fmaxf(1.0f + 2.0f * cq * xy + cq * cq * x2 * y2, MIN_NORM);
    const float pA  = ka * sA / den;
    const float pB  = kb * sB / den;

    // ||res||^2 and projection
    const float url2_from_y2 = 0.0f; // (not needed; url2 folded into y2/sB)
    (void)url2_from_y2;
    // res = pA*att + pB*rl ; need rl.rl = y2 / (sB*sB)
    const float rl2 = y2 / fmaxf(sB * sB, 1e-30f);
    const float rn2 = pA*pA*u2 + 2.0f*pA*pB*adr + pB*pB*rl2;
    const float nrm = fmaxf(sqrtf(rn2), MIN_NORM);
    const float pr  = (nrm > maxnorm) ? maxnorm / nrm : 1.0f;
    const float rx2 = rn2 * pr * pr;

    const float vnorm = fmaxf(sqrtf(sv), MIN_NORM);
    const float sxv   = (pA * atl + pB * rtl) * pr;
    const float xv    = sxv / vnorm;
    const float gamma = tanh_pos(sqrt_c * vnorm) / vnorm;
    const float k1 = 1.0f - 2.0f * cq * gamma * xv + cq * gamma * gamma;
    const float k2 = 1.0f - cq * rx2;
    const float num = sqrtf(fmaxf(k1*k1*rx2 + k2*k2*gamma*gamma
                                  - 2.0f*k1*k2*gamma*xv, 0.0f));
    const float dden = fmaxf(1.0f - 2.0f*cq*gamma*xv + cq*cq*gamma*gamma*rx2, MIN_NORM);
    float arg = sqrt_c * num / dden;
    arg = fminf(fmaxf(arg, -1.0f + 1e-5f), 1.0f - 1e-5f);
    const float ath  = 0.5f * __logf((1.0f + arg) / (1.0f - arg));
    const float dist = 2.0f * ath / sqrt_c;
    const float dist2 = dist * dist;

    if (hl == 0) {
        __builtin_nontemporal_store(bias_head[h] + bias_tail[t] + dist2, out_pred + qid);
    }
}

extern "C" void kernel_launch(void* const* d_in, const int* in_sizes, int n_in,
                              void* d_out, int out_size, void* d_ws, size_t ws_size,
                              hipStream_t stream) {
    const int*   queries     = (const int*)  d_in[0];
    const float* entity_emb  = (const float*)d_in[1];
    const float* rel_emb     = (const float*)d_in[2];
    const float* bias_head   = (const float*)d_in[3];
    const float* bias_tail   = (const float*)d_in[4];
    const float* c_arr       = (const float*)d_in[5];
    const float* att_rel_emb = (const float*)d_in[6];
    const float* context_emb = (const float*)d_in[7];
    float* out = (float*)d_out;

    // ws layout
    float*          ws_scal = (float*)d_ws;                           // R*8 f32 = 32 KB
    unsigned short* ws_rot  = (unsigned short*)(ws_scal + (size_t)R * 8);   // R*256 u16
    unsigned short* ws_ref  = ws_rot + (size_t)R * D;
    unsigned short* ws_ctx  = ws_ref + (size_t)R * D;

    prep_kernel<<<R, 64, 0, stream>>>(rel_emb, c_arr, att_rel_emb, context_emb,
                                      ws_scal, ws_rot, ws_ref, ws_ctx);

    const int queries_per_block = 8;
    const int grid = (NQ + queries_per_block - 1) / queries_per_block;
    atth_kernel<<<grid, 256, 0, stream>>>(queries, entity_emb, rel_emb,
                                          bias_head, bias_tail,
                                          ws_scal, ws_rot, ws_ref, ws_ctx, out);
}